// Round 14
// baseline (872.165 us; speedup 1.0000x reference)
//
#include <hip/hip_runtime.h>

// DIAGNOSTIC ROUND. R1-R12: five distinct scan structures all land at
// ~167-176us for 512 MB (~3 TB/s) while pure-write fills in the same graph
// hit 6.5 TB/s. This round isolates WHY with two named copy kernels:
//   A diag_copy_linear : 2x linear grid-stride copy in->out (1 GB, m13 style)
//   B diag_copy_strided: 2x copy with the scan's exact 4MB-slab pattern (1 GB)
//   C psp_scan_kernel  : exact scan (R11, absmax 0), runs LAST and overwrites
//                        all of out -> correctness unaffected by A/B.
// rocprof separates the three dispatches by name+duration.
//  A==B~205us -> pattern innocent (mixed ceiling ~5TB/s); gap is scan-specific
//  B >> A     -> 4MB-slab access pattern is the limiter -> fix layout next
//  A==B~340us -> environment mixed-stream ceiling IS ~3TB/s -> scan = roofline

typedef float f4 __attribute__((ext_vector_type(4)));

#define NC4 (512 * 2048 / 4)        // 262144 f4 columns per timestep
#define TOT (64 * NC4)              // 16,777,216 f4 = 256 MB
#define CHUNK 16
#define NCHUNK 4

// ---- A: linear grid-stride copy, 2 passes (1 GB). No __restrict__ so the
// compiler cannot prove in[] unchanged and merge the passes.
__global__ __launch_bounds__(256) void diag_copy_linear(const f4* in, f4* out) {
    const size_t stride = (size_t)gridDim.x * 256;
    for (int pass = 0; pass < 2; ++pass) {
        for (size_t i = (size_t)blockIdx.x * 256 + threadIdx.x; i < (size_t)TOT;
             i += stride)
            out[i] = in[i];
    }
}

// ---- B: slab-strided copy, 2 passes (1 GB): per thread 16 loads 4MB apart,
// then 16 stores 4MB apart — the scan's exact address pattern, no dependence.
__global__ __launch_bounds__(256) void diag_copy_strided(const f4* in, f4* out) {
    const int idx = blockIdx.x * 256 + (int)threadIdx.x;   // [0, NC4)
    for (int pass = 0; pass < 2; ++pass) {
        for (int c = 0; c < NCHUNK; ++c) {
            const size_t b = (size_t)(c * CHUNK) * NC4 + idx;
            f4 v[CHUNK];
#pragma unroll
            for (int j = 0; j < CHUNK; ++j) v[j] = in[b + (size_t)j * NC4];
#pragma unroll
            for (int j = 0; j < CHUNK; ++j) out[b + (size_t)j * NC4] = v[j];
        }
    }
}

// ---- C: exact scan (R11 structure, absmax 0.0). Runs last; overwrites out.
__global__ __launch_bounds__(256) void psp_scan_kernel(
    const f4* __restrict__ in, f4* __restrict__ out) {
    const int idx = blockIdx.x * 256 + (int)threadIdx.x;   // [0, NC4)
    f4 acc = {0.f, 0.f, 0.f, 0.f};
    for (int c = 0; c < NCHUNK; ++c) {
        const size_t b = (size_t)(c * CHUNK) * NC4 + idx;
        f4 v[CHUNK];
#pragma unroll
        for (int j = 0; j < CHUNK; ++j) v[j] = in[b + (size_t)j * NC4];
#pragma unroll
        for (int j = 0; j < CHUNK; ++j) {
            acc = 0.5f * (acc + v[j]);
            v[j] = acc;
        }
#pragma unroll
        for (int j = 0; j < CHUNK; ++j) out[b + (size_t)j * NC4] = v[j];
    }
}

extern "C" void kernel_launch(void* const* d_in, const int* in_sizes, int n_in,
                              void* d_out, int out_size, void* d_ws, size_t ws_size,
                              hipStream_t stream) {
    const f4* in = (const f4*)d_in[0];
    f4* out = (f4*)d_out;
    diag_copy_linear<<<2048, 256, 0, stream>>>(in, out);
    diag_copy_strided<<<NC4 / 256, 256, 0, stream>>>(in, out);
    psp_scan_kernel<<<NC4 / 256, 256, 0, stream>>>(in, out);
}